// Round 2
// baseline (445.868 us; speedup 1.0000x reference)
//
#include <hip/hip_runtime.h>
#include <math.h>

// Problem constants
#define Bdim 16
#define Cdim 32
#define Ndim 207
#define CINd 64
#define COUTd 64

// strides (floats)
#define X_B (Cdim * Ndim * CINd)            // 423936
#define X_C (Ndim * CINd)                   // 13248
#define W_C (Ndim * CINd * COUTd * 2)       // 1695744
#define W_N (CINd * COUTd * 2)              // 8192

// 1/sqrt(1+1e-5)
#define BN_EVAL 0.9999950000374997f

typedef float v2f __attribute__((ext_vector_type(2)));

__global__ __launch_bounds__(256, 4)
void fused_multilinear(const float* __restrict__ x,
                       const float* __restrict__ rw,   // res_weight
                       const float* __restrict__ rb,   // res_bias [C*N]
                       const float* __restrict__ mw,   // mlp_w [COUT][CIN]
                       const float* __restrict__ mb,   // mlp_b [COUT]
                       const float* __restrict__ gw,   // gate_w [COUT][CIN]
                       const float* __restrict__ gb,   // gate_b [COUT]
                       const float* __restrict__ ow,   // order_w [2]
                       const float* __restrict__ obp,  // order_b [1]
                       float* __restrict__ out)
{
    // mg[i][o] = {mlp_w[o][i], gate_w[o][i]}, row stride 64 float2.
    // Unpadded: lanes read consecutive float2 -> 2-way bank aliasing (free on
    // gfx950, m136). 32768 B exactly -> 5 blocks/CU LDS-wise.
    __shared__ float2 mg[64 * 64];

    const int cn = blockIdx.x;
    const int c  = cn / Ndim;
    const int n  = cn % Ndim;
    const int o  = threadIdx.x & 63;
    // wave-uniform batch-group: wave w handles b = 4w .. 4w+3
    const int bg = __builtin_amdgcn_readfirstlane((int)(threadIdx.x >> 6));

    // --- stage mlp_w/gate_w transposed into LDS (coalesced global reads) ---
    for (int t = threadIdx.x; t < 4096; t += 256) {
        const int oo = t >> 6;       // row of mw/gw
        const int ii = t & 63;       // col
        mg[ii * 64 + oo] = make_float2(mw[t], gw[t]);
    }
    __syncthreads();

    // per-block bases
    const float* wbase = rw + (size_t)c * W_C + (size_t)n * W_N + (size_t)(o * 2);
    const float* xb0   = x + (size_t)c * X_C + (size_t)(n * CINd);

    const float* xr[4];
#pragma unroll
    for (int j = 0; j < 4; ++j)
        xr[j] = xb0 + (size_t)(bg * 4 + j) * X_B;

    v2f acc01[4];   // {sum x*W0, sum x^2*W1}
    v2f accSG[4];   // {mlp, gate}
#pragma unroll
    for (int j = 0; j < 4; ++j) { acc01[j] = (v2f)(0.f); accSG[j] = (v2f)(0.f); }

    // ---- software-pipelined main loop: prefetch chunk k+1 while computing k ----
    float2 wcur[8], wnxt[8];
    float4 xcur[4][2], xnxt[4][2];

    // prefetch chunk 0
#pragma unroll
    for (int k = 0; k < 8; ++k)
        wcur[k] = *(const float2*)(wbase + (size_t)k * 128);
#pragma unroll
    for (int j = 0; j < 4; ++j) {
        xcur[j][0] = *(const float4*)(xr[j] + 0);
        xcur[j][1] = *(const float4*)(xr[j] + 4);
    }

#pragma unroll
    for (int c8 = 0; c8 < 8; ++c8) {
        const int i0 = c8 * 8;

        if (c8 < 7) {
            const int i1 = i0 + 8;
#pragma unroll
            for (int k = 0; k < 8; ++k)
                wnxt[k] = *(const float2*)(wbase + (size_t)(i1 + k) * 128);
#pragma unroll
            for (int j = 0; j < 4; ++j) {
                xnxt[j][0] = *(const float4*)(xr[j] + i1);
                xnxt[j][1] = *(const float4*)(xr[j] + i1 + 4);
            }
        }

#pragma unroll
        for (int k = 0; k < 8; ++k) {
            const int i = i0 + k;
            const v2f wv = { wcur[k].x, wcur[k].y };           // {W0, W1}
            const float2 mraw = mg[i * 64 + o];
            const v2f mv = { mraw.x, mraw.y };                 // {mlp, gate}
            const float4 a = xcur[0][k >> 2];                  // placeholder; real per-j below
#pragma unroll
            for (int j = 0; j < 4; ++j) {
                const float4 q = xcur[j][k >> 2];
                const float xb = (k & 3) == 0 ? q.x : (k & 3) == 1 ? q.y
                               : (k & 3) == 2 ? q.z : q.w;
                const v2f xx  = { xb, xb * xb };               // 1 mul
                acc01[j] += xx * wv;                           // v_pk_fma_f32
                const v2f xbb = { xb, xb };
                accSG[j] += xbb * mv;                          // v_pk_fma_f32
            }
            (void)a;
        }

        if (c8 < 7) {
#pragma unroll
            for (int k = 0; k < 8; ++k) wcur[k] = wnxt[k];
#pragma unroll
            for (int j = 0; j < 4; ++j) {
                xcur[j][0] = xnxt[j][0];
                xcur[j][1] = xnxt[j][1];
            }
        }
    }

    // --- epilogue ---
    const float rbias = rb[c * Ndim + n];
    const float ow0 = ow[0], ow1 = ow[1], obias = obp[0];
    const float mbias = mb[o];
    const float gbias = gb[o];

#pragma unroll
    for (int j = 0; j < 4; ++j) {
        const int b = bg * 4 + j;
        float uniq = (acc01[j].x + rbias) * ow0
                   + (BN_EVAL * acc01[j].y + rbias) * ow1
                   + obias;
        uniq *= 0.125f;  // SCALE/4 = (64/(2*64))/4

        const float xs = accSG[j].x + mbias;
        const float zg = accSG[j].y + gbias;
        const float g  = 1.0f / (1.0f + __expf(-zg));

        const size_t idx = (size_t)b * X_B + (size_t)c * X_C + (size_t)(n * CINd) + o;
        out[idx] = g * uniq + (1.0f - g) * xs + x[idx];
    }
}

extern "C" void kernel_launch(void* const* d_in, const int* in_sizes, int n_in,
                              void* d_out, int out_size, void* d_ws, size_t ws_size,
                              hipStream_t stream)
{
    const float* x   = (const float*)d_in[0];
    const float* rw  = (const float*)d_in[1];
    const float* rb  = (const float*)d_in[2];
    const float* mw  = (const float*)d_in[3];
    const float* mb  = (const float*)d_in[4];
    const float* gw  = (const float*)d_in[5];
    const float* gb  = (const float*)d_in[6];
    const float* ow  = (const float*)d_in[7];
    const float* ob  = (const float*)d_in[8];
    float* out = (float*)d_out;

    fused_multilinear<<<dim3(Cdim * Ndim), dim3(256), 0, stream>>>(
        x, rw, rb, mw, mb, gw, gb, ow, ob, out);
}